// Round 14
// baseline (2067.079 us; speedup 1.0000x reference)
//
#include <hip/hip_runtime.h>

#define NB 2048
#define NT 1024

typedef float vf4 __attribute__((ext_vector_type(4)));

__device__ __forceinline__ float tanh_fast(float x) {
    return fmaf(2.0f, __builtin_amdgcn_rcpf(1.0f + __builtin_amdgcn_exp2f(-2.8853900817779268f * x)), -1.0f);
}

// force a wave-uniform float into an SGPR
__device__ __forceinline__ float sgpr_f(float v) {
    return __int_as_float(__builtin_amdgcn_readfirstlane(__float_as_int(v)));
}

__global__ void zero_loss_kernel(float* out) { out[0] = 0.0f; }

// one vf4 weight frag x one vf4 h frag -> 2 accumulators (v_fma_f32, full rate)
#define MAC4(a0, a1, W, H) \
  a0 = fmaf((W).x, (H).x, a0); a1 = fmaf((W).y, (H).y, a1); \
  a0 = fmaf((W).z, (H).z, a0); a1 = fmaf((W).w, (H).w, a1);

// Block = 2 waves = one sequence; lane (w, q=l>>4) owns gate row R = q*32+u,
// u = 16w+(l&15). ALL MACs are v_fma_f32 (2 cyc, measured) -- v_dot2_f32_f16
// turned out to issue at ~quarter rate on gfx950 and was the real limiter in
// R4-R13. Weights: 24 volatile vf4 f32 loads (cannot be re-sourced). pred is
// folded into cell 0 per-lane (w_out in SGPRs via readfirstlane), removing
// the 5-shfl reduce + LDS broadcast from the serial chain.
__global__ __launch_bounds__(128) __attribute__((amdgpu_waves_per_eu(4, 4)))
void decoder_lstm_kernel(const float* __restrict__ seq,    // (B,T,1)
                         const float* __restrict__ z,      // (B,32)
                         const float* __restrict__ w_ih0,  // (128,1)
                         const float* __restrict__ w_hh0,  // (128,32)
                         const float* __restrict__ b_ih0,  // (128,)
                         const float* __restrict__ b_hh0,  // (128,)
                         const float* __restrict__ w_ih1,  // (128,32)
                         const float* __restrict__ w_hh1,  // (128,32)
                         const float* __restrict__ b_ih1,  // (128,)
                         const float* __restrict__ b_hh1,  // (128,)
                         const float* __restrict__ w_out,  // (1,32)
                         const float* __restrict__ b_out,  // (1,)
                         float* __restrict__ out)          // [0]=loss, [1..]=recovered
{
    const int tid = threadIdx.x;
    const int w   = tid >> 6;          // wave: units [16w, 16w+16)
    const int l   = tid & 63;
    const int q   = l >> 4;            // gate 0=i 1=f 2=g 3=o
    const int u   = 16 * w + (l & 15); // hidden unit
    const int R   = q * 32 + u;        // global gate row
    const int b   = blockIdx.x;

    __shared__ __align__(16) float h0buf[2][32];   // ping-pong h0 (f32)
    __shared__ __align__(16) float h1buf[2][32];   // ping-pong h1 (f32)

    // ---- 96 f32 weight registers via volatile loads (no re-sourcing) ----
    const volatile vf4* W0 = (const volatile vf4*)&w_hh0[R * 32];
    const volatile vf4* WI = (const volatile vf4*)&w_ih1[R * 32];
    const volatile vf4* WH = (const volatile vf4*)&w_hh1[R * 32];
    vf4 w00=W0[0], w01=W0[1], w02=W0[2], w03=W0[3], w04=W0[4], w05=W0[5], w06=W0[6], w07=W0[7];
    vf4 wi0=WI[0], wi1=WI[1], wi2=WI[2], wi3=WI[3], wi4=WI[4], wi5=WI[5], wi6=WI[6], wi7=WI[7];
    vf4 wh0=WH[0], wh1=WH[1], wh2=WH[2], wh3=WH[3], wh4=WH[4], wh5=WH[5], wh6=WH[6], wh7=WH[7];

    // w_out: wave-uniform -> 32 SGPRs (zero VGPR cost; 1-SGPR operand legal)
    float so[32];
#pragma unroll
    for (int k = 0; k < 32; ++k) so[k] = sgpr_f(w_out[k]);

    const float wih0R  = w_ih0[R];
    const float bOut   = b_out[0];
    // fold pred = a + bOut into the bias: v0 = wih0R*a + (bias0 + wih0R*bOut)
    const float bias0f = fmaf(wih0R, bOut, b_ih0[R] + b_hh0[R]);
    const float bias1  = b_ih1[R] + b_hh1[R];

    // activation personality: gate 2 (g) is tanh, others sigmoid
    const float m2 = (q == 2) ? 1.0f : 0.0f;
    const float eM = (q == 2) ? -2.8853900817779268f : -1.4426950408889634f;

    const float cz = z[(size_t)b * 32 + u];
    float c0 = cz, c1 = cz;
    if (l < 16) { h0buf[0][u] = cz; h1buf[0][u] = cz; }
    float sse = 0.0f, xreg = 0.0f;

    const float* seq_b = seq + (size_t)b * NT;
    float* out_b = out + 1 + (size_t)b * NT;

    __syncthreads();

    for (int t = 0; t < NT; ++t) {
        const int par = t & 1;
        const float* h1p = h1buf[par];
        const float* h0p = h0buf[par];

        // ---- a = w_out . h1(t-1)  (per-lane, SGPR x broadcast-LDS, 32 fmaf)
        float a0 = 0.0f, a1 = 0.0f;
#pragma unroll
        for (int kk = 0; kk < 32; kk += 4) {
            vf4 F = *(const vf4*)&h1p[kk];
            a0 = fmaf(so[kk + 0], F.x, a0);
            a1 = fmaf(so[kk + 1], F.y, a1);
            a0 = fmaf(so[kk + 2], F.z, a0);
            a1 = fmaf(so[kk + 3], F.w, a1);
        }
        const float a  = a0 + a1;
        const float af = t ? a : -bOut;   // t=0: reference pred0 = 0

        // deferred output/sse for step t-1 (pred(t-1) = a + bOut)
        if (w == 0) {
            if ((t & 63) == 1) xreg = seq_b[(t - 1) + l];   // covers steps t-1..t+62
            if (t) {
                float predv = a + bOut;
                out_b[t - 1] = predv;                       // uniform: 1 transaction
                float d  = xreg - predv;
                float ds = (((t - 1) & 63) == l) ? d : 0.0f;
                sse = fmaf(ds, d, sse);
            }
        }

        // ---- cell 0: v = W_hh0[R].h0 + wih0R*af + bias0f
        float g0 = 0.f, g1 = 0.f, g2 = 0.f, g3 = 0.f;
        {
            vf4 F;
            F = *(const vf4*)&h0p[0];  MAC4(g0, g1, w00, F);
            F = *(const vf4*)&h0p[4];  MAC4(g2, g3, w01, F);
            F = *(const vf4*)&h0p[8];  MAC4(g0, g1, w02, F);
            F = *(const vf4*)&h0p[12]; MAC4(g2, g3, w03, F);
            F = *(const vf4*)&h0p[16]; MAC4(g0, g1, w04, F);
            F = *(const vf4*)&h0p[20]; MAC4(g2, g3, w05, F);
            F = *(const vf4*)&h0p[24]; MAC4(g0, g1, w06, F);
            F = *(const vf4*)&h0p[28]; MAC4(g2, g3, w07, F);
        }
        float v  = ((g0 + g1) + (g2 + g3)) + fmaf(wih0R, af, bias0f);
        float s  = __builtin_amdgcn_rcpf(1.0f + __builtin_amdgcn_exp2f(eM * v));
        float av = fmaf(m2, s - 1.0f, s);           // sig(v) or tanh(v)

        // gate combine (valid on q=0 lanes; bounded garbage elsewhere)
        float x16 = __shfl_xor(av, 16);   // sig(f)
        float x32 = __shfl_xor(av, 32);   // tanh(g)
        float x48 = __shfl_xor(av, 48);   // sig(o)
        c0 = fmaf(x16, c0, av * x32);
        float h0n = x48 * tanh_fast(c0);
        if (l < 16) h0buf[par ^ 1][u] = h0n;
        __syncthreads();                 // h0n exchange

        // ---- cell 1: v1 = W_ih1[R].h0n + W_hh1[R].h1 + bias1
        const float* n0p = h0buf[par ^ 1];
        float d0 = 0.f, d1 = 0.f, d2 = 0.f, d3 = 0.f;
        {
            vf4 F;
            F = *(const vf4*)&n0p[0];  MAC4(d0, d1, wi0, F);
            F = *(const vf4*)&h1p[0];  MAC4(d2, d3, wh0, F);
            F = *(const vf4*)&n0p[4];  MAC4(d0, d1, wi1, F);
            F = *(const vf4*)&h1p[4];  MAC4(d2, d3, wh1, F);
            F = *(const vf4*)&n0p[8];  MAC4(d0, d1, wi2, F);
            F = *(const vf4*)&h1p[8];  MAC4(d2, d3, wh2, F);
            F = *(const vf4*)&n0p[12]; MAC4(d0, d1, wi3, F);
            F = *(const vf4*)&h1p[12]; MAC4(d2, d3, wh3, F);
            F = *(const vf4*)&n0p[16]; MAC4(d0, d1, wi4, F);
            F = *(const vf4*)&h1p[16]; MAC4(d2, d3, wh4, F);
            F = *(const vf4*)&n0p[20]; MAC4(d0, d1, wi5, F);
            F = *(const vf4*)&h1p[20]; MAC4(d2, d3, wh5, F);
            F = *(const vf4*)&n0p[24]; MAC4(d0, d1, wi6, F);
            F = *(const vf4*)&h1p[24]; MAC4(d2, d3, wh6, F);
            F = *(const vf4*)&n0p[28]; MAC4(d0, d1, wi7, F);
            F = *(const vf4*)&h1p[28]; MAC4(d2, d3, wh7, F);
        }
        float v1  = ((d0 + d1) + (d2 + d3)) + bias1;
        float s1  = __builtin_amdgcn_rcpf(1.0f + __builtin_amdgcn_exp2f(eM * v1));
        float av1 = fmaf(m2, s1 - 1.0f, s1);

        float y16 = __shfl_xor(av1, 16);
        float y32 = __shfl_xor(av1, 32);
        float y48 = __shfl_xor(av1, 48);
        c1 = fmaf(y16, c1, av1 * y32);
        float h1n = y48 * tanh_fast(c1);
        if (l < 16) h1buf[par ^ 1][u] = h1n;
        __syncthreads();                 // h1n ready for next step's a-dot
    }

    // ---- epilogue: pred(NT-1) from final h1 (in h1buf[0], NT even)
    {
        const float* h1f = h1buf[0];
        float a0 = 0.0f, a1 = 0.0f;
#pragma unroll
        for (int kk = 0; kk < 32; kk += 4) {
            vf4 F = *(const vf4*)&h1f[kk];
            a0 = fmaf(so[kk + 0], F.x, a0);
            a1 = fmaf(so[kk + 1], F.y, a1);
            a0 = fmaf(so[kk + 2], F.z, a0);
            a1 = fmaf(so[kk + 3], F.w, a1);
        }
        if (w == 0) {
            float predv = (a0 + a1) + bOut;
            out_b[NT - 1] = predv;
            float d  = xreg - predv;                 // lane 63 holds x[1023]
            float ds = (l == 63) ? d : 0.0f;
            sse = fmaf(ds, d, sse);

            // wave-wide SSE reduction, one atomic per block
            sse += __shfl_xor(sse, 1);
            sse += __shfl_xor(sse, 2);
            sse += __shfl_xor(sse, 4);
            sse += __shfl_xor(sse, 8);
            sse += __shfl_xor(sse, 16);
            sse += __shfl_xor(sse, 32);
            if (l == 0) atomicAdd(out, sse * (1.0f / ((float)NB * (float)NT)));
        }
    }
}

extern "C" void kernel_launch(void* const* d_in, const int* in_sizes, int n_in,
                              void* d_out, int out_size, void* d_ws, size_t ws_size,
                              hipStream_t stream) {
    const float* seq   = (const float*)d_in[0];
    const float* z     = (const float*)d_in[1];
    // d_in[2] = lengths (unused; reference ignores it)
    const float* w_ih0 = (const float*)d_in[3];
    const float* w_hh0 = (const float*)d_in[4];
    const float* b_ih0 = (const float*)d_in[5];
    const float* b_hh0 = (const float*)d_in[6];
    const float* w_ih1 = (const float*)d_in[7];
    const float* w_hh1 = (const float*)d_in[8];
    const float* b_ih1 = (const float*)d_in[9];
    const float* b_hh1 = (const float*)d_in[10];
    const float* w_out = (const float*)d_in[11];
    const float* b_out = (const float*)d_in[12];
    float* out = (float*)d_out;

    hipLaunchKernelGGL(zero_loss_kernel, dim3(1), dim3(1), 0, stream, out);
    hipLaunchKernelGGL(decoder_lstm_kernel, dim3(NB), dim3(128), 0, stream,
                       seq, z, w_ih0, w_hh0, b_ih0, b_hh0,
                       w_ih1, w_hh1, b_ih1, b_hh1, w_out, b_out, out);
}